// Round 4
// baseline (238.599 us; speedup 1.0000x reference)
//
#include <hip/hip_runtime.h>
#include <math.h>

#define MAX_SLOTS 64
#define L 4096

// ws layout (bytes)
#define OFF_CNT   0
#define OFF_LIST  64          // 64 ints
#define OFF_FSUB  512         // 2*64*66*66*4 = 2230272 (zero-padded border)
#define OFF_K5    2230784     // 2*64*64*25*4 = 1638400  [b][c][slot][25]
#define OFF_SFP   3869184     // 4*2*64*4096*4 = 8388608 [chunk][b][slot][P]
#define OFF_W     12257792    // 2*64*4096*4 = 2097152

// ---- K1: subsample + zero padding + (block 0) mask->active list ----
__global__ __launch_bounds__(256) void k_fsub(const float* __restrict__ in,
                                              const int* __restrict__ mask,
                                              int* __restrict__ cnt,
                                              int* __restrict__ list,
                                              float* __restrict__ fsub) {
    int idx = blockIdx.x * 256 + threadIdx.x;      // 524288 data cells
    int j = idx & 63;
    int i = (idx >> 6) & 63;
    int c = (idx >> 12) & 63;
    int b = idx >> 18;
    float v = in[(((b * 128 + c) * 128) + 2 * i) * 128 + 2 * j];
    fsub[(size_t)b * 278784 + c * 4356 + (i + 1) * 66 + (j + 1)] = v;
    // zero the 260 pad cells of each of the 128 planes (33280 total)
    if (idx < 33280) {
        int plane = idx / 260;
        int r = idx - plane * 260;
        int pb = plane >> 6, pc = plane & 63;
        int row, col;
        if (r < 66) { row = 0; col = r; }
        else if (r < 132) { row = 65; col = r - 66; }
        else { int rr = r - 132; row = (rr >> 1) + 1; col = (rr & 1) ? 65 : 0; }
        fsub[(size_t)pb * 278784 + pc * 4356 + row * 66 + col] = 0.f;
    }
    if (blockIdx.x == 0) {
        __shared__ int lcnt;
        if (threadIdx.x == 0) lcnt = 0;
        __syncthreads();
        for (int q = threadIdx.x; q < L; q += 256) {
            int qi = q >> 6, qj = q & 63;
            bool allz = true;
            for (int dy = -1; dy <= 1; ++dy)
                for (int dx = -1; dx <= 1; ++dx) {
                    int y = qi + dy, x = qj + dx;
                    if (y >= 0 && y < 64 && x >= 0 && x < 64)
                        allz = allz && (mask[y * 64 + x] == 0);
                }
            if (allz) {
                int p = atomicAdd(&lcnt, 1);
                if (p < MAX_SLOTS) list[p] = q;
            }
        }
        __syncthreads();
        if (threadIdx.x == 0) *cnt = (lcnt < MAX_SLOTS) ? lcnt : MAX_SLOTS;
    }
}

// ---- K2: per (b,slot) build collapsed 5x5 kernel K5[b][c][slot][25] ----
__global__ __launch_bounds__(256) void k_prep(const float* __restrict__ fsub,
                                              const int* __restrict__ cnt,
                                              const int* __restrict__ list,
                                              float* __restrict__ K5) {
    int slot = blockIdx.x, b = blockIdx.y;
    int tid = threadIdx.x;
    int nact = min(*cnt, MAX_SLOTS);
    if (slot >= nact) {
        for (int t = tid; t < 1600; t += 256) {
            int c = t / 25, e = t - c * 25;
            K5[(((size_t)b * 64 + c) * 64 + slot) * 25 + e] = 0.f;
        }
        return;
    }
    __shared__ float patch9[9 * 576];
    __shared__ float red[256];
    __shared__ float s_inv;
    __shared__ int flag9[9];
    int Q = list[slot];
    const float* F = fsub + (size_t)b * 278784;
    int t0 = tid, t1 = tid + 256, t2 = tid + 512;
    for (int combo = 0; combo < 9; ++combo) {
        __syncthreads();
        int d2 = combo / 3 - 1, d1 = combo % 3 - 1;
        int XQ = ((Q & 63) << 6) + (Q >> 6) + d2;
        int flag = (XQ >= 0 && XQ < L);
        int R = 0;
        if (flag) {
            int YQ = ((XQ & 63) << 6) + (XQ >> 6);
            R = YQ + d1;
            flag = (R >= 0 && R < L);
        }
        if (tid == 0) flag9[combo] = flag;
        if (!flag) continue;
        int ri = R >> 6, rj = R & 63;
        const float* Fp = F + (ri) * 66 + (rj);
        auto ld = [&](int t) -> float {
            int c = t / 9; int tap = t - c * 9;
            int dy = tap / 3, dx = tap - dy * 3;   // 0..2
            return Fp[c * 4356 + dy * 66 + dx];    // data (ri+dy-1, rj+dx-1)
        };
        float v0 = ld(t0), v1 = ld(t1), v2 = (tid < 64) ? ld(t2) : 0.f;
        red[tid] = v0 * v0 + v1 * v1 + v2 * v2;
        __syncthreads();
        if (tid < 64) {
            float a = red[tid] + red[tid + 64] + red[tid + 128] + red[tid + 192];
            for (int o = 32; o > 0; o >>= 1) a += __shfl_xor(a, o);
            if (tid == 0) s_inv = 1.f / fmaxf(sqrtf(a), 1e-8f);
        }
        __syncthreads();
        float inv = s_inv;
        float* dst = patch9 + combo * 576;
        dst[t0] = v0 * inv; dst[t1] = v1 * inv;
        if (tid < 64) dst[t2] = v2 * inv;
    }
    __syncthreads();
    // K5[c][oy,ox] = sum_{dy,dx} patch9[(oy-dy, ox-dx)][c][dy,dx]
    for (int t = tid; t < 1600; t += 256) {
        int c = t / 25, e = t - c * 25;
        int oy = e / 5 - 2, ox = e - (e / 5) * 5 - 2;
        float s = 0.f;
        for (int dy = -1; dy <= 1; ++dy) {
            int dd2 = oy - dy; if (dd2 < -1 || dd2 > 1) continue;
            for (int dx = -1; dx <= 1; ++dx) {
                int dd1 = ox - dx; if (dd1 < -1 || dd1 > 1) continue;
                int combo = (dd2 + 1) * 3 + (dd1 + 1);
                if (flag9[combo])
                    s += patch9[combo * 576 + c * 9 + (dy + 1) * 3 + (dx + 1)];
            }
        }
        K5[(((size_t)b * 64 + c) * 64 + slot) * 25 + e] = s;
    }
}

// ---- K3: interior 5x5 conv, 16 slots in registers, LDS-tiled ----
__global__ __launch_bounds__(256) void k_conv(const float* __restrict__ fsub,
                                              const int* __restrict__ cnt,
                                              const float* __restrict__ K5,
                                              float* __restrict__ sfp) {
    __shared__ float tile[544];           // 8 rows x 68 cols; tile[r][c] = data(r0+r-2, c-2)
    int r0 = blockIdx.x * 4;              // pixel rows r0..r0+3
    int ch = blockIdx.y;                  // c-chunk (16 channels)
    int b  = blockIdx.z;
    int cc0 = ch * 16;
    int tid = threadIdx.x;
    int ty = tid >> 6, tx = tid & 63;
    int i = r0 + ty, j = tx;
    bool border = (i == 0 || i == 63 || j == 0 || j == 63);
    int nact = min(*cnt, MAX_SLOTS);
    const float* F = fsub + (size_t)b * 278784;
    int ra = tid / 68,  ca = tid - ra * 68;
    int rb = (tid + 256) / 68, cb = (tid + 256) - rb * 68;
    int rc = (tid + 512) / 68, cc = (tid + 512) - rc * 68;
    int offA = min(max(r0 + ra - 1, 0), 65) * 66 + min(max(ca - 1, 0), 65);
    int offB = min(max(r0 + rb - 1, 0), 65) * 66 + min(max(cb - 1, 0), 65);
    int offC = min(max(r0 + rc - 1, 0), 65) * 66 + min(max(cc - 1, 0), 65);
    int P = (i << 6) + j;
    for (int s0 = 0; s0 < nact; s0 += 16) {
        float acc[16];
        #pragma unroll
        for (int s = 0; s < 16; ++s) acc[s] = 0.f;
        const float* F0 = F + cc0 * 4356;
        float va = F0[offA], vb = F0[offB], vc = (tid < 32) ? F0[offC] : 0.f;
        for (int c = 0; c < 16; ++c) {
            __syncthreads();
            tile[tid] = va; tile[tid + 256] = vb;
            if (tid < 32) tile[tid + 512] = vc;
            __syncthreads();
            if (c < 15) {
                const float* Fn = F + (cc0 + c + 1) * 4356;
                va = Fn[offA]; vb = Fn[offB];
                if (tid < 32) vc = Fn[offC];
            }
            float win[25];
            #pragma unroll
            for (int k = 0; k < 25; ++k)
                win[k] = tile[(ty + k / 5) * 68 + tx + (k % 5)];   // FIX: no +2
            const float* kc = K5 + (((size_t)b * 64 + cc0 + c) * 64 + s0) * 25;
            #pragma unroll
            for (int s = 0; s < 16; ++s) {
                #pragma unroll
                for (int k = 0; k < 25; ++k)
                    acc[s] += kc[s * 25 + k] * win[k];
            }
        }
        #pragma unroll
        for (int s = 0; s < 16; ++s)
            sfp[(((size_t)ch * 2 + b) * 64 + (s0 + s)) * 4096 + P] = border ? 0.f : acc[s];
    }
}

// ---- K4: exact per-combo scores for the 252 border pixels ----
__global__ __launch_bounds__(256) void k_border(const float* __restrict__ fsub,
                                                const int* __restrict__ cnt,
                                                const int* __restrict__ list,
                                                float* __restrict__ sfp) {
    int combo = blockIdx.x, slot = blockIdx.y, b = blockIdx.z;
    int tid = threadIdx.x;
    int nact = min(*cnt, MAX_SLOTS);
    if (slot >= nact) return;
    int d2 = combo / 3 - 1, d1 = combo % 3 - 1;
    int Q = list[slot];
    int XQ = ((Q & 63) << 6) + (Q >> 6) + d2;
    if (XQ < 0 || XQ >= L) return;
    int YQ = ((XQ & 63) << 6) + (XQ >> 6);
    int R = YQ + d1;
    if (R < 0 || R >= L) return;
    int ri = R >> 6, rj = R & 63;
    const float* F = fsub + (size_t)b * 278784;
    __shared__ float patch[576];
    __shared__ float red[256];
    __shared__ float s_inv;
    const float* Fp = F + ri * 66 + rj;
    auto ld = [&](int t) -> float {
        int c = t / 9; int tap = t - c * 9;
        int dy = tap / 3, dx = tap - dy * 3;
        return Fp[c * 4356 + dy * 66 + dx];
    };
    float v0 = ld(tid), v1 = ld(tid + 256), v2 = (tid < 64) ? ld(tid + 512) : 0.f;
    red[tid] = v0 * v0 + v1 * v1 + v2 * v2;
    __syncthreads();
    if (tid < 64) {
        float a = red[tid] + red[tid + 64] + red[tid + 128] + red[tid + 192];
        for (int o = 32; o > 0; o >>= 1) a += __shfl_xor(a, o);
        if (tid == 0) s_inv = 1.f / fmaxf(sqrtf(a), 1e-8f);
    }
    __syncthreads();
    float inv = s_inv;
    patch[tid] = v0 * inv; patch[tid + 256] = v1 * inv;
    if (tid < 64) patch[tid + 512] = v2 * inv;
    __syncthreads();
    if (tid >= 252) return;
    int i, j;
    if (tid < 64)       { i = 0;  j = tid; }
    else if (tid < 128) { i = 63; j = tid - 64; }
    else if (tid < 190) { i = tid - 127; j = 0; }
    else                { i = tid - 189; j = 63; }
    int P = (i << 6) + j;
    int XP = (j << 6) + i + d2;
    if (XP < 0 || XP >= L) return;
    int YP = ((XP & 63) << 6) + (XP >> 6);
    int Z = YP + d1;
    if (Z < 0 || Z >= L) return;
    int pi = Z >> 6, pj = Z & 63;
    const float* Fz = F + pi * 66 + pj;
    float dot = 0.f;
    #pragma unroll 4
    for (int c = 0; c < 64; ++c) {
        const float* Fc = Fz + c * 4356;
        const float* pc = patch + c * 9;
        dot += Fc[0] * pc[0]   + Fc[1] * pc[1]   + Fc[2] * pc[2];
        dot += Fc[66] * pc[3]  + Fc[67] * pc[4]  + Fc[68] * pc[5];
        dot += Fc[132] * pc[6] + Fc[133] * pc[7] + Fc[134] * pc[8];
    }
    atomicAdd(&sfp[((size_t)b * 64 + slot) * 4096 + P], dot);
}

// ---- K5: sum partials + softmax over slots (masked rows analytic) ----
__global__ __launch_bounds__(256) void k_soft(const int* __restrict__ cnt,
                                              const float* __restrict__ sfp,
                                              float* __restrict__ wbuf) {
    int idx = blockIdx.x * 256 + threadIdx.x;   // 2*4096
    int b = idx >> 12; int P = idx & 4095;
    int nact = min(*cnt, MAX_SLOTS);
    float M = 0.f;
    for (int s = 0; s < nact; ++s) {
        float v = 0.f;
        #pragma unroll
        for (int ch = 0; ch < 4; ++ch)
            v += sfp[(((size_t)ch * 2 + b) * 64 + s) * 4096 + P];
        float l = 10.f * v;
        wbuf[((size_t)b * 64 + s) * 4096 + P] = l;
        M = fmaxf(M, l);
    }
    float denom = (float)(L - nact) * expf(-M);
    for (int s = 0; s < nact; ++s) {
        float e = expf(wbuf[((size_t)b * 64 + s) * 4096 + P] - M);
        wbuf[((size_t)b * 64 + s) * 4096 + P] = e;
        denom += e;
    }
    float inv = 1.f / denom;
    for (int s = 0; s < nact; ++s)
        wbuf[((size_t)b * 64 + s) * 4096 + P] *= inv;
}

// ---- K6: aggregation + passthrough, 8 channels/block ----
__global__ __launch_bounds__(128) void k_out(const float* __restrict__ in,
                                             const int* __restrict__ mask,
                                             const int* __restrict__ cnt,
                                             const int* __restrict__ list,
                                             const float* __restrict__ wbuf,
                                             float* __restrict__ out) {
    __shared__ float pat8[MAX_SLOTS * 128];  // [s][cc(8)][16 taps]
    int u = blockIdx.x, cg = blockIdx.y, b = blockIdx.z;
    int c0 = cg * 8;
    int tid = threadIdx.x;                   // v
    int nact = min(*cnt, MAX_SLOTS);
    const float* inb0 = in + (size_t)b * 2097152 + (size_t)c0 * 16384;
    for (int t = tid; t < nact * 128; t += 128) {
        int s = t >> 7; int r = t & 127;
        int cc = r >> 4; int e = r & 15; int aa = e >> 2; int bb = e & 3;
        int q = list[s]; int qi = q >> 6, qj = q & 63;
        int row = 2 * qi - 1 + aa, col = 2 * qj - 1 + bb;
        float v = (row >= 0 && row < 128 && col >= 0 && col < 128)
                  ? inb0[(size_t)cc * 16384 + row * 128 + col] : 0.f;
        pat8[t] = v;
    }
    __syncthreads();
    int v = tid;
    float y[8];
    #pragma unroll
    for (int cc = 0; cc < 8; ++cc) y[cc] = 0.f;
    if (mask[(u >> 1) * 64 + (v >> 1)] != 0 && nact > 0) {
        int pa = (u + 1) & 1, pb = (v + 1) & 1;
        int i0 = (u + 1 - pa) >> 1, j0 = (v + 1 - pb) >> 1;
        for (int s = 0; s < nact; ++s) {
            const float* wrow = wbuf + ((size_t)b * 64 + s) * 4096;
            const float* ps = pat8 + s * 128;
            #pragma unroll
            for (int di = 0; di < 2; ++di) {
                int i = i0 - di; if (i < 0 || i >= 64) continue;
                int aa = pa + 2 * di;
                #pragma unroll
                for (int dj = 0; dj < 2; ++dj) {
                    int j = j0 - dj; if (j < 0 || j >= 64) continue;
                    float wv = wrow[(i << 6) + j];
                    int tap = aa * 4 + pb + 2 * dj;
                    #pragma unroll
                    for (int cc = 0; cc < 8; ++cc)
                        y[cc] += wv * ps[cc * 16 + tap];
                }
            }
        }
        #pragma unroll
        for (int cc = 0; cc < 8; ++cc) y[cc] *= 0.25f;
    }
    size_t ob = (size_t)(b * 192) * 16384 + (size_t)u * 128 + v;
    #pragma unroll
    for (int cc = 0; cc < 8; ++cc) {
        int c = c0 + cc;
        float val = in[(size_t)(b * 128 + c) * 16384 + u * 128 + v];
        out[ob + (size_t)c * 16384] = val;            // b_full
        out[ob + (size_t)(c + 64) * 16384] = val;     // f_full
        out[ob + (size_t)(c + 128) * 16384] = y[cc];  // y
    }
}

extern "C" void kernel_launch(void* const* d_in, const int* in_sizes, int n_in,
                              void* d_out, int out_size, void* d_ws, size_t ws_size,
                              hipStream_t stream) {
    const float* in = (const float*)d_in[0];
    const int* mask = (const int*)d_in[1];
    float* out = (float*)d_out;
    char* ws = (char*)d_ws;
    int* cnt    = (int*)(ws + OFF_CNT);
    int* list   = (int*)(ws + OFF_LIST);
    float* fsub = (float*)(ws + OFF_FSUB);
    float* K5   = (float*)(ws + OFF_K5);
    float* sfp  = (float*)(ws + OFF_SFP);
    float* wbuf = (float*)(ws + OFF_W);

    k_fsub<<<2048, 256, 0, stream>>>(in, mask, cnt, list, fsub);
    k_prep<<<dim3(MAX_SLOTS, 2), 256, 0, stream>>>(fsub, cnt, list, K5);
    k_conv<<<dim3(16, 4, 2), 256, 0, stream>>>(fsub, cnt, K5, sfp);
    k_border<<<dim3(9, MAX_SLOTS, 2), 256, 0, stream>>>(fsub, cnt, list, sfp);
    k_soft<<<32, 256, 0, stream>>>(cnt, sfp, wbuf);
    k_out<<<dim3(128, 8, 2), 128, 0, stream>>>(in, mask, cnt, list, wbuf, out);
}

// Round 5
// 174.558 us; speedup vs baseline: 1.3669x; 1.3669x over previous
//
#include <hip/hip_runtime.h>
#include <math.h>

#define MAX_SLOTS 64
#define L 4096

// ws layout (bytes)
#define OFF_CNT   0
#define OFF_LIST  64          // 64 ints
#define OFF_FSUB  512         // 2*64*66*66*4 = 2230272 (zero-padded border)
#define OFF_K5    2230784     // 2*64*64*25*4 = 1638400  [b][c][slot][25]
#define OFF_SF    3869184     // 2*64*4096*4 = 2097152   [b][slot][P]
#define OFF_W     5966336     // 2*64*4096*4 = 2097152

// ---- K1: subsample + zero padding + zero sf + (block 0) mask->active list ----
__global__ __launch_bounds__(256) void k_fsub(const float* __restrict__ in,
                                              const int* __restrict__ mask,
                                              int* __restrict__ cnt,
                                              int* __restrict__ list,
                                              float* __restrict__ fsub,
                                              float* __restrict__ sf) {
    int idx = blockIdx.x * 256 + threadIdx.x;      // 524288 data cells
    int j = idx & 63;
    int i = (idx >> 6) & 63;
    int c = (idx >> 12) & 63;
    int b = idx >> 18;
    float v = in[(((b * 128 + c) * 128) + 2 * i) * 128 + 2 * j];
    fsub[(size_t)b * 278784 + c * 4356 + (i + 1) * 66 + (j + 1)] = v;
    sf[idx] = 0.f;                                 // sf is exactly 524288 floats
    // zero the 260 pad cells of each of the 128 planes (33280 total)
    if (idx < 33280) {
        int plane = idx / 260;
        int r = idx - plane * 260;
        int pb = plane >> 6, pc = plane & 63;
        int row, col;
        if (r < 66) { row = 0; col = r; }
        else if (r < 132) { row = 65; col = r - 66; }
        else { int rr = r - 132; row = (rr >> 1) + 1; col = (rr & 1) ? 65 : 0; }
        fsub[(size_t)pb * 278784 + pc * 4356 + row * 66 + col] = 0.f;
    }
    if (blockIdx.x == 0) {
        __shared__ int lcnt;
        if (threadIdx.x == 0) lcnt = 0;
        __syncthreads();
        for (int q = threadIdx.x; q < L; q += 256) {
            int qi = q >> 6, qj = q & 63;
            bool allz = true;
            for (int dy = -1; dy <= 1; ++dy)
                for (int dx = -1; dx <= 1; ++dx) {
                    int y = qi + dy, x = qj + dx;
                    if (y >= 0 && y < 64 && x >= 0 && x < 64)
                        allz = allz && (mask[y * 64 + x] == 0);
                }
            if (allz) {
                int p = atomicAdd(&lcnt, 1);
                if (p < MAX_SLOTS) list[p] = q;
            }
        }
        __syncthreads();
        if (threadIdx.x == 0) *cnt = (lcnt < MAX_SLOTS) ? lcnt : MAX_SLOTS;
    }
}

// ---- K2: per (b,slot) build collapsed 5x5 kernel K5[b][c][slot][25] ----
// combos handled one-per-wave (no serialization barriers), then K5 build.
__global__ __launch_bounds__(256) void k_prep(const float* __restrict__ fsub,
                                              const int* __restrict__ cnt,
                                              const int* __restrict__ list,
                                              float* __restrict__ K5) {
    int slot = blockIdx.x, b = blockIdx.y;
    int tid = threadIdx.x;
    int nact = min(*cnt, MAX_SLOTS);
    if (slot >= nact) {
        for (int t = tid; t < 1600; t += 256) {
            int c = t / 25, e = t - c * 25;
            K5[(((size_t)b * 64 + c) * 64 + slot) * 25 + e] = 0.f;
        }
        return;
    }
    __shared__ float patch9[9 * 576];
    __shared__ int flag9[9];
    if (tid < 9) flag9[tid] = 0;
    __syncthreads();
    int Q = list[slot];
    const float* F = fsub + (size_t)b * 278784;
    int w = tid >> 6, lane = tid & 63;
    for (int combo = w; combo < 9; combo += 4) {
        int d2 = combo / 3 - 1, d1 = combo % 3 - 1;
        int XQ = ((Q & 63) << 6) + (Q >> 6) + d2;
        if (XQ < 0 || XQ >= L) continue;
        int YQ = ((XQ & 63) << 6) + (XQ >> 6);
        int R = YQ + d1;
        if (R < 0 || R >= L) continue;
        if (lane == 0) flag9[combo] = 1;
        int ri = R >> 6, rj = R & 63;
        const float* Fp = F + ri * 66 + rj;
        float vals[9]; float ss = 0.f;
        #pragma unroll
        for (int k = 0; k < 9; ++k) {
            int t = lane + (k << 6);               // 0..575
            int c = t / 9; int tap = t - c * 9;
            int dy = tap / 3, dx = tap - dy * 3;
            float v = Fp[c * 4356 + dy * 66 + dx]; // data (ri+dy-1, rj+dx-1)
            vals[k] = v; ss += v * v;
        }
        for (int o = 32; o > 0; o >>= 1) ss += __shfl_xor(ss, o);
        float inv = 1.f / fmaxf(sqrtf(ss), 1e-8f);
        float* dst = patch9 + combo * 576;
        #pragma unroll
        for (int k = 0; k < 9; ++k) dst[lane + (k << 6)] = vals[k] * inv;
    }
    __syncthreads();
    // K5[c][oy,ox] = sum_{dy,dx} patch9[(oy-dy, ox-dx)][c][dy,dx]
    for (int t = tid; t < 1600; t += 256) {
        int c = t / 25, e = t - c * 25;
        int oy = e / 5 - 2, ox = e - (e / 5) * 5 - 2;
        float s = 0.f;
        for (int dy = -1; dy <= 1; ++dy) {
            int dd2 = oy - dy; if (dd2 < -1 || dd2 > 1) continue;
            for (int dx = -1; dx <= 1; ++dx) {
                int dd1 = ox - dx; if (dd1 < -1 || dd1 > 1) continue;
                int combo = (dd2 + 1) * 3 + (dd1 + 1);
                if (flag9[combo])
                    s += patch9[combo * 576 + c * 9 + (dy + 1) * 3 + (dx + 1)];
            }
        }
        K5[(((size_t)b * 64 + c) * 64 + slot) * 25 + e] = s;
    }
}

// ---- K3: interior 5x5 conv — one wave per (row, 4-ch chunk, b), no barriers ----
__global__ __launch_bounds__(64) void k_conv(const float* __restrict__ fsub,
                                             const int* __restrict__ cnt,
                                             const float* __restrict__ K5,
                                             float* __restrict__ sf) {
    int r  = blockIdx.x + 1;          // interior rows 1..62
    int cg = blockIdx.y;              // 16 chunks of 4 channels
    int b  = blockIdx.z;
    int j  = threadIdx.x;             // column 0..63
    int nact = min(*cnt, MAX_SLOTS);
    if (nact == 0) return;
    int jc = min(max(j, 1), 62);      // clamp address for masked lanes 0/63
    const float* F = fsub + (size_t)b * 278784;
    int base = (r - 1) * 66 + (jc - 1);   // padded (r-1, jc-1) = data (r-2, jc-2)
    bool active = (j >= 1 && j <= 62);
    int P = (r << 6) + j;
    for (int s0 = 0; s0 < nact; s0 += 16) {
        float acc[16];
        #pragma unroll
        for (int s = 0; s < 16; ++s) acc[s] = 0.f;
        #pragma unroll
        for (int cc = 0; cc < 4; ++cc) {
            int c = cg * 4 + cc;
            const float* Fc = F + c * 4356 + base;
            float win[25];
            #pragma unroll
            for (int dy = 0; dy < 5; ++dy)
                #pragma unroll
                for (int dx = 0; dx < 5; ++dx)
                    win[dy * 5 + dx] = Fc[dy * 66 + dx];
            const float* kc = K5 + (((size_t)b * 64 + c) * 64 + s0) * 25;  // wave-uniform
            #pragma unroll
            for (int s = 0; s < 16; ++s) {
                #pragma unroll
                for (int k = 0; k < 25; ++k)
                    acc[s] += kc[s * 25 + k] * win[k];
            }
        }
        if (active) {
            int smax = min(16, nact - s0);
            for (int s = 0; s < smax; ++s)
                atomicAdd(&sf[((size_t)b * 64 + (s0 + s)) * 4096 + P], acc[s]);
        }
    }
}

// ---- K4: exact per-combo scores for the 252 border pixels ----
__global__ __launch_bounds__(256) void k_border(const float* __restrict__ fsub,
                                                const int* __restrict__ cnt,
                                                const int* __restrict__ list,
                                                float* __restrict__ sf) {
    int combo = blockIdx.x, slot = blockIdx.y, b = blockIdx.z;
    int tid = threadIdx.x;
    int nact = min(*cnt, MAX_SLOTS);
    if (slot >= nact) return;
    int d2 = combo / 3 - 1, d1 = combo % 3 - 1;
    int Q = list[slot];
    int XQ = ((Q & 63) << 6) + (Q >> 6) + d2;
    if (XQ < 0 || XQ >= L) return;
    int YQ = ((XQ & 63) << 6) + (XQ >> 6);
    int R = YQ + d1;
    if (R < 0 || R >= L) return;
    int ri = R >> 6, rj = R & 63;
    const float* F = fsub + (size_t)b * 278784;
    __shared__ float patch[576];
    __shared__ float red[256];
    __shared__ float s_inv;
    const float* Fp = F + ri * 66 + rj;
    auto ld = [&](int t) -> float {
        int c = t / 9; int tap = t - c * 9;
        int dy = tap / 3, dx = tap - dy * 3;
        return Fp[c * 4356 + dy * 66 + dx];
    };
    float v0 = ld(tid), v1 = ld(tid + 256), v2 = (tid < 64) ? ld(tid + 512) : 0.f;
    red[tid] = v0 * v0 + v1 * v1 + v2 * v2;
    __syncthreads();
    if (tid < 64) {
        float a = red[tid] + red[tid + 64] + red[tid + 128] + red[tid + 192];
        for (int o = 32; o > 0; o >>= 1) a += __shfl_xor(a, o);
        if (tid == 0) s_inv = 1.f / fmaxf(sqrtf(a), 1e-8f);
    }
    __syncthreads();
    float inv = s_inv;
    patch[tid] = v0 * inv; patch[tid + 256] = v1 * inv;
    if (tid < 64) patch[tid + 512] = v2 * inv;
    __syncthreads();
    if (tid >= 252) return;
    int i, j;
    if (tid < 64)       { i = 0;  j = tid; }
    else if (tid < 128) { i = 63; j = tid - 64; }
    else if (tid < 190) { i = tid - 127; j = 0; }
    else                { i = tid - 189; j = 63; }
    int P = (i << 6) + j;
    int XP = (j << 6) + i + d2;
    if (XP < 0 || XP >= L) return;
    int YP = ((XP & 63) << 6) + (XP >> 6);
    int Z = YP + d1;
    if (Z < 0 || Z >= L) return;
    int pi = Z >> 6, pj = Z & 63;
    const float* Fz = F + pi * 66 + pj;
    float dot = 0.f;
    #pragma unroll 4
    for (int c = 0; c < 64; ++c) {
        const float* Fc = Fz + c * 4356;
        const float* pc = patch + c * 9;
        dot += Fc[0] * pc[0]   + Fc[1] * pc[1]   + Fc[2] * pc[2];
        dot += Fc[66] * pc[3]  + Fc[67] * pc[4]  + Fc[68] * pc[5];
        dot += Fc[132] * pc[6] + Fc[133] * pc[7] + Fc[134] * pc[8];
    }
    atomicAdd(&sf[((size_t)b * 64 + slot) * 4096 + P], dot);
}

// ---- K5: softmax over slots (masked rows analytic) ----
__global__ __launch_bounds__(256) void k_soft(const int* __restrict__ cnt,
                                              const float* __restrict__ sf,
                                              float* __restrict__ wbuf) {
    int idx = blockIdx.x * 256 + threadIdx.x;   // 2*4096
    int b = idx >> 12; int P = idx & 4095;
    int nact = min(*cnt, MAX_SLOTS);
    float M = 0.f;
    for (int s = 0; s < nact; ++s) {
        float l = 10.f * sf[((size_t)b * 64 + s) * 4096 + P];
        M = fmaxf(M, l);
    }
    float denom = (float)(L - nact) * expf(-M);
    for (int s = 0; s < nact; ++s) {
        float e = expf(10.f * sf[((size_t)b * 64 + s) * 4096 + P] - M);
        wbuf[((size_t)b * 64 + s) * 4096 + P] = e;
        denom += e;
    }
    float inv = 1.f / denom;
    for (int s = 0; s < nact; ++s)
        wbuf[((size_t)b * 64 + s) * 4096 + P] *= inv;
}

// ---- K6: aggregation + passthrough, 8 channels/block ----
__global__ __launch_bounds__(128) void k_out(const float* __restrict__ in,
                                             const int* __restrict__ mask,
                                             const int* __restrict__ cnt,
                                             const int* __restrict__ list,
                                             const float* __restrict__ wbuf,
                                             float* __restrict__ out) {
    __shared__ float pat8[MAX_SLOTS * 128];  // [s][cc(8)][16 taps]
    int u = blockIdx.x, cg = blockIdx.y, b = blockIdx.z;
    int c0 = cg * 8;
    int tid = threadIdx.x;                   // v
    int nact = min(*cnt, MAX_SLOTS);
    const float* inb0 = in + (size_t)b * 2097152 + (size_t)c0 * 16384;
    for (int t = tid; t < nact * 128; t += 128) {
        int s = t >> 7; int r = t & 127;
        int cc = r >> 4; int e = r & 15; int aa = e >> 2; int bb = e & 3;
        int q = list[s]; int qi = q >> 6, qj = q & 63;
        int row = 2 * qi - 1 + aa, col = 2 * qj - 1 + bb;
        float v = (row >= 0 && row < 128 && col >= 0 && col < 128)
                  ? inb0[(size_t)cc * 16384 + row * 128 + col] : 0.f;
        pat8[t] = v;
    }
    __syncthreads();
    int v = tid;
    float y[8];
    #pragma unroll
    for (int cc = 0; cc < 8; ++cc) y[cc] = 0.f;
    if (mask[(u >> 1) * 64 + (v >> 1)] != 0 && nact > 0) {
        int pa = (u + 1) & 1, pb = (v + 1) & 1;
        int i0 = (u + 1 - pa) >> 1, j0 = (v + 1 - pb) >> 1;
        for (int s = 0; s < nact; ++s) {
            const float* wrow = wbuf + ((size_t)b * 64 + s) * 4096;
            const float* ps = pat8 + s * 128;
            #pragma unroll
            for (int di = 0; di < 2; ++di) {
                int i = i0 - di; if (i < 0 || i >= 64) continue;
                int aa = pa + 2 * di;
                #pragma unroll
                for (int dj = 0; dj < 2; ++dj) {
                    int j = j0 - dj; if (j < 0 || j >= 64) continue;
                    float wv = wrow[(i << 6) + j];
                    int tap = aa * 4 + pb + 2 * dj;
                    #pragma unroll
                    for (int cc = 0; cc < 8; ++cc)
                        y[cc] += wv * ps[cc * 16 + tap];
                }
            }
        }
        #pragma unroll
        for (int cc = 0; cc < 8; ++cc) y[cc] *= 0.25f;
    }
    size_t ob = (size_t)(b * 192) * 16384 + (size_t)u * 128 + v;
    #pragma unroll
    for (int cc = 0; cc < 8; ++cc) {
        int c = c0 + cc;
        float val = in[(size_t)(b * 128 + c) * 16384 + u * 128 + v];
        out[ob + (size_t)c * 16384] = val;            // b_full
        out[ob + (size_t)(c + 64) * 16384] = val;     // f_full
        out[ob + (size_t)(c + 128) * 16384] = y[cc];  // y
    }
}

extern "C" void kernel_launch(void* const* d_in, const int* in_sizes, int n_in,
                              void* d_out, int out_size, void* d_ws, size_t ws_size,
                              hipStream_t stream) {
    const float* in = (const float*)d_in[0];
    const int* mask = (const int*)d_in[1];
    float* out = (float*)d_out;
    char* ws = (char*)d_ws;
    int* cnt    = (int*)(ws + OFF_CNT);
    int* list   = (int*)(ws + OFF_LIST);
    float* fsub = (float*)(ws + OFF_FSUB);
    float* K5   = (float*)(ws + OFF_K5);
    float* sf   = (float*)(ws + OFF_SF);
    float* wbuf = (float*)(ws + OFF_W);

    k_fsub<<<2048, 256, 0, stream>>>(in, mask, cnt, list, fsub, sf);
    k_prep<<<dim3(MAX_SLOTS, 2), 256, 0, stream>>>(fsub, cnt, list, K5);
    k_conv<<<dim3(62, 16, 2), 64, 0, stream>>>(fsub, cnt, K5, sf);
    k_border<<<dim3(9, MAX_SLOTS, 2), 256, 0, stream>>>(fsub, cnt, list, sf);
    k_soft<<<32, 256, 0, stream>>>(cnt, sf, wbuf);
    k_out<<<dim3(128, 8, 2), 128, 0, stream>>>(in, mask, cnt, list, wbuf, out);
}